// Round 17
// baseline (232.316 us; speedup 1.0000x reference)
//
#include <hip/hip_runtime.h>
#include <cstdint>
#include <cstddef>

#define B_ 2
#define S_ 2048
#define HID_ 1024
#define NH_ 8
#define NKV_ 2
#define HD_ 256
#define ROT_ 128
#define TOK_ (B_ * S_)
#define SCALE_ 0.0625f

typedef __attribute__((ext_vector_type(8))) short s16x8;
typedef __attribute__((ext_vector_type(4))) float f32x4;

__device__ __forceinline__ float bf2f(short u) {
  unsigned t = ((unsigned)(unsigned short)u) << 16;
  float f;
  __builtin_memcpy(&f, &t, 4);
  return f;
}
__device__ __forceinline__ short f2bf(float f) {
  unsigned u;
  __builtin_memcpy(&u, &f, 4);
  u += 0x7fffu + ((u >> 16) & 1);
  return (short)(u >> 16);
}

// async global->LDS 16B (gfx950). LDS dest is wave-uniform base + lane*16.
__device__ __forceinline__ void gl16(const void* g, void* l) {
  __builtin_amdgcn_global_load_lds((const __attribute__((address_space(1))) int*)g,
                                   (__attribute__((address_space(3))) int*)l, 16, 0, 0);
}

// ---------------- elementwise cast fp32 -> bf16 ----------------
__global__ __launch_bounds__(256) void k_cast(const float* __restrict__ in,
                                              short* __restrict__ out, int n) {
  int i = blockIdx.x * 256 + threadIdx.x;
  if (i < n) out[i] = f2bf(in[i]);
}

// ---------------- tiled transpose + cast: in[R][C] fp32 -> out[C][R] bf16 ----------------
__global__ __launch_bounds__(256) void k_wtrans(const float* __restrict__ in,
                                                short* __restrict__ out, int R, int C) {
  __shared__ short tile[32][33];
  int tx = threadIdx.x & 31, ty = threadIdx.x >> 5;
  int r0 = blockIdx.y * 32, c0 = blockIdx.x * 32;
#pragma unroll
  for (int p = 0; p < 4; ++p)
    tile[ty + p * 8][tx] = f2bf(in[(size_t)(r0 + ty + p * 8) * C + c0 + tx]);
  __syncthreads();
#pragma unroll
  for (int p = 0; p < 4; ++p)
    out[(size_t)(c0 + ty + p * 8) * R + r0 + tx] = tile[tx][ty + p * 8];
}

// ---------------- V transpose: kvp v-part -> Vtg[b*2+kvh][256][2048] bf16 ----------------
__global__ __launch_bounds__(256) void k_vtrans(const short* __restrict__ kvp,
                                                short* __restrict__ Vtg) {
  __shared__ short tile[32][33];
  int bh = blockIdx.z;
  int b = bh >> 1, kvh = bh & 1;
  int s0 = blockIdx.x * 32, d0 = blockIdx.y * 32;
  int tx = threadIdx.x & 31, ty = threadIdx.x >> 5;
#pragma unroll
  for (int p = 0; p < 4; ++p) {
    int sr = ty + p * 8;
    tile[sr][tx] = kvp[(size_t)(b * S_ + s0 + sr) * 1024 + 512 + kvh * 256 + d0 + tx];
  }
  __syncthreads();
#pragma unroll
  for (int p = 0; p < 4; ++p) {
    int dr = ty + p * 8;
    Vtg[((size_t)bh * 256 + d0 + dr) * 2048 + s0 + tx] = tile[tx][dr];
  }
}

// ---------------- GEMM 128x128, BK=64, 2-phase double-buffered gl16 pipeline --------
template <int OUT_BF16>
__global__ __launch_bounds__(256, 2) void k_gemm_bt(const short* __restrict__ A,
                                                    const short* __restrict__ Bt,
                                                    void* __restrict__ Cv, int M, int N,
                                                    int K) {
  extern __shared__ char smem[];
  const int tid = threadIdx.x;
  const int bm = blockIdx.y * 128, bn = blockIdx.x * 128;
  const int w = tid >> 6, lane = tid & 63, lo = lane & 15, hi = lane >> 4;
  const int wr = (w >> 1) * 64, wc = (w & 1) * 64;
  f32x4 acc[4][4] = {};

  auto stage = [&](int k0, int nb) {
#pragma unroll
    for (int rnd = 0; rnd < 4; ++rnd) {
      int i = rnd * 256 + tid;
      int row = i >> 3, c = i & 7;
      int src_col = (c ^ (row & 7)) * 8;
      gl16(&A[(size_t)(bm + row) * K + k0 + src_col], smem + (size_t)nb * 16384 + (size_t)i * 16);
      gl16(&Bt[(size_t)(bn + row) * K + k0 + src_col],
           smem + 32768 + (size_t)nb * 16384 + (size_t)i * 16);
    }
  };

  stage(0, 0);
  __syncthreads();
  int nb = 0;
  for (int k0 = 0; k0 < K; k0 += 64) {
    if (k0 + 64 < K) stage(k0 + 64, nb ^ 1);
    const short* As = (const short*)(smem + (size_t)nb * 16384);
    const short* Bs = (const short*)(smem + 32768 + (size_t)nb * 16384);
    s16x8 af[2][4], bfr[2][4];
#pragma unroll
    for (int kk = 0; kk < 2; ++kk) {
#pragma unroll
      for (int m = 0; m < 4; ++m) {
        int row = wr + m * 16 + lo;
        af[kk][m] = *(const s16x8*)&As[row * 64 + (((kk * 4 + hi) ^ (row & 7)) * 8)];
      }
#pragma unroll
      for (int n = 0; n < 4; ++n) {
        int row = wc + n * 16 + lo;
        bfr[kk][n] = *(const s16x8*)&Bs[row * 64 + (((kk * 4 + hi) ^ (row & 7)) * 8)];
      }
    }
#pragma unroll
    for (int kk = 0; kk < 2; ++kk)
#pragma unroll
      for (int m = 0; m < 4; ++m)
#pragma unroll
        for (int n = 0; n < 4; ++n)
          acc[m][n] =
              __builtin_amdgcn_mfma_f32_16x16x32_bf16(af[kk][m], bfr[kk][n], acc[m][n], 0, 0, 0);
    __syncthreads();
    nb ^= 1;
  }
#pragma unroll
  for (int m = 0; m < 4; ++m)
#pragma unroll
    for (int n = 0; n < 4; ++n)
#pragma unroll
      for (int r = 0; r < 4; ++r) {
        int row = bm + wr + m * 16 + hi * 4 + r;
        int col = bn + wc + n * 16 + lo;
        if (OUT_BF16)
          ((short*)Cv)[(size_t)row * N + col] = f2bf(acc[m][n][r]);
        else
          ((float*)Cv)[(size_t)row * N + col] = acc[m][n][r];
      }
}

// ---------------- GEMM 256x256, 8 waves, BK=64, 2-phase double-buffered (best) ------
template <int OUT_BF16>
__global__ __launch_bounds__(512, 1) void k_gemm256(const short* __restrict__ A,
                                                    const short* __restrict__ Bt,
                                                    void* __restrict__ Cv, int M, int N,
                                                    int K) {
  extern __shared__ char smem[];
  const int tid = threadIdx.x;
  const int bm = blockIdx.y * 256, bn = blockIdx.x * 256;
  const int w = tid >> 6, lane = tid & 63, lo = lane & 15, hi = lane >> 4;
  const int wr = (w >> 2) * 128, wc = (w & 3) * 64;
  f32x4 acc[8][4] = {};

  auto stage = [&](int k0, int nb) {
#pragma unroll
    for (int rnd = 0; rnd < 4; ++rnd) {
      int i = rnd * 512 + tid;
      int row = i >> 3, c = i & 7;
      int src_col = (c ^ (row & 7)) * 8;
      gl16(&A[(size_t)(bm + row) * K + k0 + src_col], smem + (size_t)nb * 32768 + (size_t)i * 16);
      gl16(&Bt[(size_t)(bn + row) * K + k0 + src_col],
           smem + 65536 + (size_t)nb * 32768 + (size_t)i * 16);
    }
  };

  stage(0, 0);
  __syncthreads();
  int nb = 0;
  for (int k0 = 0; k0 < K; k0 += 64) {
    if (k0 + 64 < K) stage(k0 + 64, nb ^ 1);
    const short* As = (const short*)(smem + (size_t)nb * 32768);
    const short* Bs = (const short*)(smem + 65536 + (size_t)nb * 32768);
#pragma unroll
    for (int kk = 0; kk < 2; ++kk) {
      s16x8 bfr[4];
#pragma unroll
      for (int n = 0; n < 4; ++n) {
        int row = wc + n * 16 + lo;
        bfr[n] = *(const s16x8*)&Bs[row * 64 + (((kk * 4 + hi) ^ (row & 7)) * 8)];
      }
#pragma unroll
      for (int g = 0; g < 2; ++g) {
        s16x8 af[4];
#pragma unroll
        for (int u = 0; u < 4; ++u) {
          int row = wr + (g * 4 + u) * 16 + lo;
          af[u] = *(const s16x8*)&As[row * 64 + (((kk * 4 + hi) ^ (row & 7)) * 8)];
        }
#pragma unroll
        for (int u = 0; u < 4; ++u)
#pragma unroll
          for (int n = 0; n < 4; ++n)
            acc[g * 4 + u][n] =
                __builtin_amdgcn_mfma_f32_16x16x32_bf16(af[u], bfr[n], acc[g * 4 + u][n], 0, 0, 0);
      }
    }
    __syncthreads();
    nb ^= 1;
  }
#pragma unroll
  for (int m = 0; m < 8; ++m)
#pragma unroll
    for (int n = 0; n < 4; ++n)
#pragma unroll
      for (int r = 0; r < 4; ++r) {
        int row = bm + wr + m * 16 + hi * 4 + r;
        int col = bn + wc + n * 16 + lo;
        if (OUT_BF16)
          ((short*)Cv)[(size_t)row * N + col] = f2bf(acc[m][n][r]);
        else
          ((float*)Cv)[(size_t)row * N + col] = acc[m][n][r];
      }
}

// ---------------- per-(token,head) RMSNorm + RoPE, bf16 in/out ----------------
template <int NHEAD, int IN_ROW, int IN_HS>
__global__ __launch_bounds__(256) void k_norm_rope(const short* __restrict__ xin,
                                                   const float* __restrict__ wn,
                                                   const float* __restrict__ cosb,
                                                   const float* __restrict__ sinb,
                                                   short* __restrict__ xout) {
  int blk = blockIdx.x;
  int h = blk % NHEAD;
  int ts = blk / NHEAD;
  int d = threadIdx.x;
  float x = bf2f(xin[(size_t)ts * IN_ROW + h * IN_HS + d]);
  float ss = x * x;
#pragma unroll
  for (int m = 32; m >= 1; m >>= 1) ss += __shfl_xor(ss, m);
  __shared__ float sred[4];
  __shared__ float sn[256];
  int wid = d >> 6;
  if ((d & 63) == 0) sred[wid] = ss;
  __syncthreads();
  float tot = sred[0] + sred[1] + sred[2] + sred[3];
  float nv = x * rsqrtf(tot * (1.0f / 256.0f) + 1e-6f) * (1.0f + wn[d]);
  sn[d] = nv;
  __syncthreads();
  float o;
  if (d < 128) {
    float c = cosb[(size_t)ts * 128 + d];
    float s = sinb[(size_t)ts * 128 + d];
    o = (d < 64) ? (nv * c - sn[d + 64] * s) : (nv * c + sn[d - 64] * s);
  } else {
    o = nv;
  }
  xout[(size_t)blk * 256 + d] = f2bf(o);
}

// ---------------- GQA causal flash attention, quarter-split, 2 blocks/CU ------------
// 512 blocks, 8 waves, QBLK=128, KVBLK=32 double-buffered -> LDS 64KB -> 2 blocks/CU
// (4 waves/SIMD; VGPR<=128 via launch_bounds(512,2); KVBLK=64 body measured 112).
// Block (hg, j in 0..7, c in 0..3): quarter c of qt=j (j+1 tiles) then quarter c of
// qt=15-j (16-j tiles) -> EXACTLY 17 iters. Cross-block overlap hides barrier drains.
// k_merge combines 4 partials (w_i = l_i*exp(m_i-mm); all-masked quarters self-kill).
#define ATTN_LDS 65536
__global__ __launch_bounds__(512, 2) void k_attn(const short* __restrict__ qb,
                                                 const short* __restrict__ kb,
                                                 const short* __restrict__ Vtg,
                                                 short* __restrict__ Po,
                                                 float* __restrict__ Pm,
                                                 float* __restrict__ Pl) {
  extern __shared__ char smem[];
  short* KbufS = (short*)smem;            // 2 bufs x [32 rows][32 chunks x 8] = 32KB
  short* VbufS = (short*)(smem + 32768);  // 2 bufs x [256 rows][4 chunks x 8] = 32KB

  const int raw = blockIdx.x;
  const int xcd = raw & 7, slot = raw >> 3;  // slot 0..63
  const int p = xcd >> 1, side = xcd & 1;
  const int id = side * 64 + slot;  // 0..127 within (b,kvh) stream
  const int hgi = id & 3;
  const int rest = id >> 2;  // 0..31
  const int j = rest & 7, cq = rest >> 3;  // pair j, quarter cq
  const int b = p >> 1, kvh = p & 1, h = kvh * 4 + hgi;
  const int tid = threadIdx.x;
  const int w = tid >> 6, lane = tid & 63, lo = lane & 15, hi = lane >> 4;
  const int swz = lo & 7, swz3 = lo & 3;

  const short* kbase = kb + ((size_t)(b * S_) * NKV_ + kvh) * HD_;
  const short* vbase = Vtg + (size_t)(b * 2 + kvh) * 256 * 2048;

  // stage one KVBLK=32 tile: K [32][256] 1024 slots + V^T [256][32] 1024 slots
  auto stage = [&](int kv0, int nb) {
#pragma unroll
    for (int rnd = 0; rnd < 2; ++rnd) {
      int i = rnd * 512 + tid;
      {
        int row = i >> 5, cc = i & 31;
        gl16(kbase + (size_t)(kv0 + row) * 512 + ((cc ^ (row & 7)) * 8),
             smem + (size_t)nb * 16384 + (size_t)i * 16);
      }
      {
        int row = i >> 2, cc = i & 3;
        gl16(vbase + (size_t)row * 2048 + kv0 + ((cc ^ (row & 3)) * 8),
             smem + 32768 + (size_t)nb * 16384 + (size_t)i * 16);
      }
    }
  };

  int n = 0;
#pragma unroll 1
  for (int part = 0; part < 2; ++part) {
    const int qt = part ? (15 - j) : j;
    const int nQ = qt + 1;                 // quarter length in KVBLK-32 tiles
    const int t_begin = cq * nQ;
    const int t_end = t_begin + nQ;
    const int q0 = qt * 128;

    s16x8 qf[8];
    {
      size_t base = ((size_t)((b * S_ + q0 + w * 16 + lo) * NH_) + h) * HD_;
#pragma unroll
      for (int t = 0; t < 8; ++t) qf[t] = *(const s16x8*)&qb[base + t * 32 + hi * 8];
    }
    f32x4 acc[16];
#pragma unroll
    for (int t = 0; t < 16; ++t) acc[t] = (f32x4){0.f, 0.f, 0.f, 0.f};
    float m_run = -1e30f, l_run = 0.f;
    const int qrow = q0 + w * 16 + lo;

    if (part == 0) {
      stage(t_begin * 32, 0);
      __syncthreads();
    }
    // part 1: buffer n already holds its first tile (prefetched in part0's last iter)

#pragma unroll 1
    for (int it = t_begin; it < t_end; ++it) {
      const int kv0 = it * 32;
      if (it + 1 < t_end)
        stage(kv0 + 32, n ^ 1);
      else if (part == 0)
        stage(cq * (16 - j) * 32, n ^ 1);  // prefetch part1's first tile

      const short* Kb = KbufS + n * 8192;
      const short* Vb = VbufS + n * 8192;

      // S^T = K @ Q^T over HD=256 (swapped operands), 2 n-tiles of 16 kv
      f32x4 sacc[2] = {};
#pragma unroll
      for (int nt = 0; nt < 2; ++nt) {
        s16x8 kf[8];
#pragma unroll
        for (int t = 0; t < 8; ++t)
          kf[t] = *(const s16x8*)&Kb[(nt * 16 + lo) * 256 + (((t * 4 + hi) ^ swz) * 8)];
#pragma unroll
        for (int t = 0; t < 8; ++t)
          sacc[nt] = __builtin_amdgcn_mfma_f32_16x16x32_bf16(kf[t], qf[t], sacc[nt], 0, 0, 0);
      }

      // in-register softmax
      float pv[2][4];
      float mx = -1e30f;
#pragma unroll
      for (int nt = 0; nt < 2; ++nt)
#pragma unroll
        for (int r = 0; r < 4; ++r) {
          int kv = kv0 + nt * 16 + hi * 4 + r;
          float s = sacc[nt][r] * SCALE_;
          if (kv > qrow) s = -1e30f;
          pv[nt][r] = s;
          mx = fmaxf(mx, s);
        }
      mx = fmaxf(mx, __shfl_xor(mx, 16));
      mx = fmaxf(mx, __shfl_xor(mx, 32));
      if (!__all(mx <= m_run + 8.f)) {  // T13 defer-rescale
        float mnew = fmaxf(m_run, mx);
        float fs = __expf(m_run - mnew);
        m_run = mnew;
        l_run *= fs;
        float f0 = __shfl(fs, 4 * hi + 0);
        float f1 = __shfl(fs, 4 * hi + 1);
        float f2 = __shfl(fs, 4 * hi + 2);
        float f3 = __shfl(fs, 4 * hi + 3);
#pragma unroll
        for (int t = 0; t < 16; ++t) {
          acc[t][0] *= f0;
          acc[t][1] *= f1;
          acc[t][2] *= f2;
          acc[t][3] *= f3;
        }
      }
      float rs = 0.f;
#pragma unroll
      for (int nt = 0; nt < 2; ++nt)
#pragma unroll
        for (int r = 0; r < 4; ++r) {
          pv[nt][r] = __expf(pv[nt][r] - m_run);
          rs += pv[nt][r];
        }
      rs += __shfl_xor(rs, 16);
      rs += __shfl_xor(rs, 32);
      l_run += rs;

      // pack P to bf16 pairs
      int pk0[2], pk1[2];
#pragma unroll
      for (int nt = 0; nt < 2; ++nt) {
        asm("v_cvt_pk_bf16_f32 %0, %1, %2" : "=v"(pk0[nt]) : "v"(pv[nt][0]), "v"(pv[nt][1]));
        asm("v_cvt_pk_bf16_f32 %0, %1, %2" : "=v"(pk1[nt]) : "v"(pv[nt][2]), "v"(pv[nt][3]));
      }

      // PV over the 32-kv tile: pa gathered via shfl; vf from V^T [256][32]
      {
        int pw[4];
#pragma unroll
        for (int dw = 0; dw < 4; ++dw) {
          int srcl = (2 * (hi & 1) + (dw >> 1)) * 16 + lo;
          int vA = __shfl((dw & 1) ? pk1[0] : pk0[0], srcl);
          int vB = __shfl((dw & 1) ? pk1[1] : pk0[1], srcl);
          pw[dw] = (hi & 2) ? vB : vA;
        }
        s16x8 pa;
        __builtin_memcpy(&pa, pw, 16);
#pragma unroll
        for (int g = 0; g < 2; ++g) {
          s16x8 vf[8];
#pragma unroll
          for (int u = 0; u < 8; ++u) {
            int t = g * 8 + u;
            vf[u] = *(const s16x8*)&Vb[(t * 16 + lo) * 32 + ((hi ^ swz3) * 8)];
          }
#pragma unroll
          for (int u = 0; u < 8; ++u) {
            int t = g * 8 + u;
            acc[t] = __builtin_amdgcn_mfma_f32_16x16x32_bf16(pa, vf[u], acc[t], 0, 0, 0);
          }
        }
      }
      __syncthreads();
      n ^= 1;
    }

    // write l-normalized bf16 partial + (m,l) per row
    const int tile4 = (((b * 8 + h) * 16 + qt) << 2) + cq;
    float linv[4];
#pragma unroll
    for (int r = 0; r < 4; ++r) {
      float lr = __shfl(l_run, 4 * hi + r);
      linv[r] = lr > 0.f ? 1.0f / lr : 0.f;
    }
#pragma unroll
    for (int t = 0; t < 16; ++t)
#pragma unroll
      for (int r = 0; r < 4; ++r)
        Po[(size_t)tile4 * 32768 + (w * 16 + hi * 4 + r) * 256 + t * 16 + lo] =
            f2bf(acc[t][r] * linv[r]);
    if (hi == 0) {
      Pm[tile4 * 128 + w * 16 + lo] = m_run;
      Pl[tile4 * 128 + w * 16 + lo] = l_run;
    }
  }
}

// ---------------- merge 4 partials + sigmoid gate -> og ----------------
__global__ __launch_bounds__(256) void k_merge(const short* __restrict__ Po,
                                               const float* __restrict__ Pm,
                                               const float* __restrict__ Pl,
                                               const short* __restrict__ qg,
                                               short* __restrict__ og) {
  const int tile = blockIdx.x >> 4, rc = blockIdx.x & 15;
  const int b = tile >> 7, h = (tile >> 4) & 7, qt = tile & 15;
  const int t = threadIdx.x;
  const int r = t >> 5, rl = rc * 8 + r, c0 = (t & 31) * 8;
  const int row = qt * 128 + rl;
  s16x8 ov[4];
  float mv[4], lv[4];
  float mm = -1e30f;
#pragma unroll
  for (int i = 0; i < 4; ++i) {
    int t4 = tile * 4 + i;
    ov[i] = *(const s16x8*)&Po[(size_t)t4 * 32768 + rl * 256 + c0];
    mv[i] = Pm[t4 * 128 + rl];
    lv[i] = Pl[t4 * 128 + rl];
    mm = fmaxf(mm, mv[i]);
  }
  float wsum = 0.f, wv[4];
#pragma unroll
  for (int i = 0; i < 4; ++i) {
    wv[i] = lv[i] * __expf(mv[i] - mm);
    wsum += wv[i];
  }
  float inv = 1.0f / wsum;
  s16x8 gv = *(const s16x8*)&qg[(size_t)(b * S_ + row) * 4096 + h * 512 + 256 + c0];
  s16x8 outv;
#pragma unroll
  for (int jj = 0; jj < 8; ++jj) {
    float o = 0.f;
#pragma unroll
    for (int i = 0; i < 4; ++i) o += wv[i] * bf2f(ov[i][jj]);
    o *= inv;
    float g = bf2f(gv[jj]);
    float sg = 1.0f / (1.0f + __expf(-g));
    outv[jj] = f2bf(o * sg);
  }
  *(s16x8*)&og[(size_t)(b * S_ + row) * 2048 + h * 256 + c0] = outv;
}

extern "C" void kernel_launch(void* const* d_in, const int* in_sizes, int n_in, void* d_out,
                              int out_size, void* d_ws, size_t ws_size, hipStream_t stream) {
  const float* hidden = (const float*)d_in[0];
  const float* cosb = (const float*)d_in[1];
  const float* sinb = (const float*)d_in[2];
  const float* Wq = (const float*)d_in[3];
  const float* Wk = (const float*)d_in[4];
  const float* Wv = (const float*)d_in[5];
  const float* Wo = (const float*)d_in[6];
  const float* qw = (const float*)d_in[7];
  const float* kw = (const float*)d_in[8];
  float* out = (float*)d_out;

  char* ws = (char*)d_ws;
  size_t off = 0;
  auto alloc = [&](size_t bytes) {
    void* p = ws + off;
    off += (bytes + 255) & ~(size_t)255;
    return p;
  };
  short* hb = (short*)alloc((size_t)TOK_ * HID_ * 2);
  short* WqT = (short*)alloc((size_t)4096 * 1024 * 2);
  short* kvT = (short*)alloc((size_t)1024 * 1024 * 2);
  short* WoT = (short*)alloc((size_t)1024 * 2048 * 2);
  short* qg = (short*)alloc((size_t)TOK_ * 4096 * 2);
  short* kvp = (short*)alloc((size_t)TOK_ * 1024 * 2);
  short* qb = (short*)alloc((size_t)TOK_ * 2048 * 2);
  short* kb = (short*)alloc((size_t)TOK_ * 512 * 2);
  short* og = (short*)alloc((size_t)TOK_ * 2048 * 2);
  short* Po = (short*)alloc((size_t)1024 * 32768 * 2);  // 1024 quarter-partials
  float* Pm = (float*)alloc((size_t)1024 * 128 * 4);
  float* Pl = (float*)alloc((size_t)1024 * 128 * 4);
  short* Vtg = WqT;  // reuse: WqT dead after GEMM1
  (void)ws_size;
  (void)in_sizes;
  (void)n_in;
  (void)out_size;

  hipFuncSetAttribute((const void*)k_attn, hipFuncAttributeMaxDynamicSharedMemorySize,
                      ATTN_LDS);
  hipFuncSetAttribute((const void*)k_gemm256<1>, hipFuncAttributeMaxDynamicSharedMemorySize,
                      131072);
  hipFuncSetAttribute((const void*)k_gemm_bt<1>, hipFuncAttributeMaxDynamicSharedMemorySize,
                      65536);
  hipFuncSetAttribute((const void*)k_gemm_bt<0>, hipFuncAttributeMaxDynamicSharedMemorySize,
                      65536);

  k_cast<<<(TOK_ * HID_ + 255) / 256, 256, 0, stream>>>(hidden, hb, TOK_ * HID_);
  k_wtrans<<<dim3(4096 / 32, 1024 / 32), 256, 0, stream>>>(Wq, WqT, 1024, 4096);
  k_wtrans<<<dim3(512 / 32, 1024 / 32), 256, 0, stream>>>(Wk, kvT, 1024, 512);
  k_wtrans<<<dim3(512 / 32, 1024 / 32), 256, 0, stream>>>(Wv, kvT + 512 * 1024, 1024, 512);
  k_wtrans<<<dim3(1024 / 32, 2048 / 32), 256, 0, stream>>>(Wo, WoT, 2048, 1024);

  k_gemm256<1><<<dim3(16, 16), 512, 131072, stream>>>(hb, WqT, qg, 4096, 4096, 1024);
  k_gemm_bt<1><<<dim3(8, 32), 256, 65536, stream>>>(hb, kvT, kvp, 4096, 1024, 1024);

  k_norm_rope<NH_, 4096, 512><<<TOK_ * NH_, 256, 0, stream>>>(qg, qw, cosb, sinb, qb);
  k_norm_rope<NKV_, 1024, 256><<<TOK_ * NKV_, 256, 0, stream>>>(kvp, kw, cosb, sinb, kb);
  k_vtrans<<<dim3(64, 8, 4), 256, 0, stream>>>(kvp, Vtg);

  k_attn<<<512, 512, ATTN_LDS, stream>>>(qb, kb, Vtg, Po, Pm, Pl);
  k_merge<<<4096, 256, 0, stream>>>(Po, Pm, Pl, qg, og);

  k_gemm_bt<0><<<dim3(8, 32), 256, 65536, stream>>>(og, WoT, out, 4096, 1024, 2048);
}

// Round 18
// 207.805 us; speedup vs baseline: 1.1180x; 1.1180x over previous
//
#include <hip/hip_runtime.h>
#include <cstdint>
#include <cstddef>

#define B_ 2
#define S_ 2048
#define HID_ 1024
#define NH_ 8
#define NKV_ 2
#define HD_ 256
#define ROT_ 128
#define TOK_ (B_ * S_)
#define SCALE_ 0.0625f

typedef __attribute__((ext_vector_type(8))) short s16x8;
typedef __attribute__((ext_vector_type(4))) float f32x4;

__device__ __forceinline__ float bf2f(short u) {
  unsigned t = ((unsigned)(unsigned short)u) << 16;
  float f;
  __builtin_memcpy(&f, &t, 4);
  return f;
}
__device__ __forceinline__ short f2bf(float f) {
  unsigned u;
  __builtin_memcpy(&u, &f, 4);
  u += 0x7fffu + ((u >> 16) & 1);
  return (short)(u >> 16);
}

// async global->LDS 16B (gfx950). LDS dest is wave-uniform base + lane*16.
__device__ __forceinline__ void gl16(const void* g, void* l) {
  __builtin_amdgcn_global_load_lds((const __attribute__((address_space(1))) int*)g,
                                   (__attribute__((address_space(3))) int*)l, 16, 0, 0);
}

// ---------------- elementwise cast fp32 -> bf16 ----------------
__global__ __launch_bounds__(256) void k_cast(const float* __restrict__ in,
                                              short* __restrict__ out, int n) {
  int i = blockIdx.x * 256 + threadIdx.x;
  if (i < n) out[i] = f2bf(in[i]);
}

// ---------------- tiled transpose + cast: in[R][C] fp32 -> out[C][R] bf16 ----------------
__global__ __launch_bounds__(256) void k_wtrans(const float* __restrict__ in,
                                                short* __restrict__ out, int R, int C) {
  __shared__ short tile[32][33];
  int tx = threadIdx.x & 31, ty = threadIdx.x >> 5;
  int r0 = blockIdx.y * 32, c0 = blockIdx.x * 32;
#pragma unroll
  for (int p = 0; p < 4; ++p)
    tile[ty + p * 8][tx] = f2bf(in[(size_t)(r0 + ty + p * 8) * C + c0 + tx]);
  __syncthreads();
#pragma unroll
  for (int p = 0; p < 4; ++p)
    out[(size_t)(c0 + ty + p * 8) * R + r0 + tx] = tile[tx][ty + p * 8];
}

// ---------------- V transpose: kvp v-part -> Vtg[b*2+kvh][256][2048] bf16 ----------------
__global__ __launch_bounds__(256) void k_vtrans(const short* __restrict__ kvp,
                                                short* __restrict__ Vtg) {
  __shared__ short tile[32][33];
  int bh = blockIdx.z;
  int b = bh >> 1, kvh = bh & 1;
  int s0 = blockIdx.x * 32, d0 = blockIdx.y * 32;
  int tx = threadIdx.x & 31, ty = threadIdx.x >> 5;
#pragma unroll
  for (int p = 0; p < 4; ++p) {
    int sr = ty + p * 8;
    tile[sr][tx] = kvp[(size_t)(b * S_ + s0 + sr) * 1024 + 512 + kvh * 256 + d0 + tx];
  }
  __syncthreads();
#pragma unroll
  for (int p = 0; p < 4; ++p) {
    int dr = ty + p * 8;
    Vtg[((size_t)bh * 256 + d0 + dr) * 2048 + s0 + tx] = tile[tx][dr];
  }
}

// ---------------- GEMM 128x128, BK=64, 2-phase double-buffered gl16 pipeline --------
template <int OUT_BF16>
__global__ __launch_bounds__(256, 2) void k_gemm_bt(const short* __restrict__ A,
                                                    const short* __restrict__ Bt,
                                                    void* __restrict__ Cv, int M, int N,
                                                    int K) {
  extern __shared__ char smem[];
  const int tid = threadIdx.x;
  const int bm = blockIdx.y * 128, bn = blockIdx.x * 128;
  const int w = tid >> 6, lane = tid & 63, lo = lane & 15, hi = lane >> 4;
  const int wr = (w >> 1) * 64, wc = (w & 1) * 64;
  f32x4 acc[4][4] = {};

  auto stage = [&](int k0, int nb) {
#pragma unroll
    for (int rnd = 0; rnd < 4; ++rnd) {
      int i = rnd * 256 + tid;
      int row = i >> 3, c = i & 7;
      int src_col = (c ^ (row & 7)) * 8;
      gl16(&A[(size_t)(bm + row) * K + k0 + src_col], smem + (size_t)nb * 16384 + (size_t)i * 16);
      gl16(&Bt[(size_t)(bn + row) * K + k0 + src_col],
           smem + 32768 + (size_t)nb * 16384 + (size_t)i * 16);
    }
  };

  stage(0, 0);
  __syncthreads();
  int nb = 0;
  for (int k0 = 0; k0 < K; k0 += 64) {
    if (k0 + 64 < K) stage(k0 + 64, nb ^ 1);
    const short* As = (const short*)(smem + (size_t)nb * 16384);
    const short* Bs = (const short*)(smem + 32768 + (size_t)nb * 16384);
    s16x8 af[2][4], bfr[2][4];
#pragma unroll
    for (int kk = 0; kk < 2; ++kk) {
#pragma unroll
      for (int m = 0; m < 4; ++m) {
        int row = wr + m * 16 + lo;
        af[kk][m] = *(const s16x8*)&As[row * 64 + (((kk * 4 + hi) ^ (row & 7)) * 8)];
      }
#pragma unroll
      for (int n = 0; n < 4; ++n) {
        int row = wc + n * 16 + lo;
        bfr[kk][n] = *(const s16x8*)&Bs[row * 64 + (((kk * 4 + hi) ^ (row & 7)) * 8)];
      }
    }
#pragma unroll
    for (int kk = 0; kk < 2; ++kk)
#pragma unroll
      for (int m = 0; m < 4; ++m)
#pragma unroll
        for (int n = 0; n < 4; ++n)
          acc[m][n] =
              __builtin_amdgcn_mfma_f32_16x16x32_bf16(af[kk][m], bfr[kk][n], acc[m][n], 0, 0, 0);
    __syncthreads();
    nb ^= 1;
  }
#pragma unroll
  for (int m = 0; m < 4; ++m)
#pragma unroll
    for (int n = 0; n < 4; ++n)
#pragma unroll
      for (int r = 0; r < 4; ++r) {
        int row = bm + wr + m * 16 + hi * 4 + r;
        int col = bn + wc + n * 16 + lo;
        if (OUT_BF16)
          ((short*)Cv)[(size_t)row * N + col] = f2bf(acc[m][n][r]);
        else
          ((float*)Cv)[(size_t)row * N + col] = acc[m][n][r];
      }
}

// ---------------- GEMM 256x256, 8 waves, BK=64, 2-phase double-buffered (best) ------
template <int OUT_BF16>
__global__ __launch_bounds__(512, 1) void k_gemm256(const short* __restrict__ A,
                                                    const short* __restrict__ Bt,
                                                    void* __restrict__ Cv, int M, int N,
                                                    int K) {
  extern __shared__ char smem[];
  const int tid = threadIdx.x;
  const int bm = blockIdx.y * 256, bn = blockIdx.x * 256;
  const int w = tid >> 6, lane = tid & 63, lo = lane & 15, hi = lane >> 4;
  const int wr = (w >> 2) * 128, wc = (w & 3) * 64;
  f32x4 acc[8][4] = {};

  auto stage = [&](int k0, int nb) {
#pragma unroll
    for (int rnd = 0; rnd < 4; ++rnd) {
      int i = rnd * 512 + tid;
      int row = i >> 3, c = i & 7;
      int src_col = (c ^ (row & 7)) * 8;
      gl16(&A[(size_t)(bm + row) * K + k0 + src_col], smem + (size_t)nb * 32768 + (size_t)i * 16);
      gl16(&Bt[(size_t)(bn + row) * K + k0 + src_col],
           smem + 65536 + (size_t)nb * 32768 + (size_t)i * 16);
    }
  };

  stage(0, 0);
  __syncthreads();
  int nb = 0;
  for (int k0 = 0; k0 < K; k0 += 64) {
    if (k0 + 64 < K) stage(k0 + 64, nb ^ 1);
    const short* As = (const short*)(smem + (size_t)nb * 32768);
    const short* Bs = (const short*)(smem + 65536 + (size_t)nb * 32768);
#pragma unroll
    for (int kk = 0; kk < 2; ++kk) {
      s16x8 bfr[4];
#pragma unroll
      for (int n = 0; n < 4; ++n) {
        int row = wc + n * 16 + lo;
        bfr[n] = *(const s16x8*)&Bs[row * 64 + (((kk * 4 + hi) ^ (row & 7)) * 8)];
      }
#pragma unroll
      for (int g = 0; g < 2; ++g) {
        s16x8 af[4];
#pragma unroll
        for (int u = 0; u < 4; ++u) {
          int row = wr + (g * 4 + u) * 16 + lo;
          af[u] = *(const s16x8*)&As[row * 64 + (((kk * 4 + hi) ^ (row & 7)) * 8)];
        }
#pragma unroll
        for (int u = 0; u < 4; ++u)
#pragma unroll
          for (int n = 0; n < 4; ++n)
            acc[g * 4 + u][n] =
                __builtin_amdgcn_mfma_f32_16x16x32_bf16(af[u], bfr[n], acc[g * 4 + u][n], 0, 0, 0);
      }
    }
    __syncthreads();
    nb ^= 1;
  }
#pragma unroll
  for (int m = 0; m < 8; ++m)
#pragma unroll
    for (int n = 0; n < 4; ++n)
#pragma unroll
      for (int r = 0; r < 4; ++r) {
        int row = bm + wr + m * 16 + hi * 4 + r;
        int col = bn + wc + n * 16 + lo;
        if (OUT_BF16)
          ((short*)Cv)[(size_t)row * N + col] = f2bf(acc[m][n][r]);
        else
          ((float*)Cv)[(size_t)row * N + col] = acc[m][n][r];
      }
}

// ---------------- per-(token,head) RMSNorm + RoPE, bf16 in/out ----------------
template <int NHEAD, int IN_ROW, int IN_HS>
__global__ __launch_bounds__(256) void k_norm_rope(const short* __restrict__ xin,
                                                   const float* __restrict__ wn,
                                                   const float* __restrict__ cosb,
                                                   const float* __restrict__ sinb,
                                                   short* __restrict__ xout) {
  int blk = blockIdx.x;
  int h = blk % NHEAD;
  int ts = blk / NHEAD;
  int d = threadIdx.x;
  float x = bf2f(xin[(size_t)ts * IN_ROW + h * IN_HS + d]);
  float ss = x * x;
#pragma unroll
  for (int m = 32; m >= 1; m >>= 1) ss += __shfl_xor(ss, m);
  __shared__ float sred[4];
  __shared__ float sn[256];
  int wid = d >> 6;
  if ((d & 63) == 0) sred[wid] = ss;
  __syncthreads();
  float tot = sred[0] + sred[1] + sred[2] + sred[3];
  float nv = x * rsqrtf(tot * (1.0f / 256.0f) + 1e-6f) * (1.0f + wn[d]);
  sn[d] = nv;
  __syncthreads();
  float o;
  if (d < 128) {
    float c = cosb[(size_t)ts * 128 + d];
    float s = sinb[(size_t)ts * 128 + d];
    o = (d < 64) ? (nv * c - sn[d + 64] * s) : (nv * c + sn[d - 64] * s);
  } else {
    o = nv;
  }
  xout[(size_t)blk * 256 + d] = f2bf(o);
}

// ---------------- GQA causal flash attention, balanced KV-split (R15, best) ---------
// 256 blocks, 8 waves, QBLK=128. Block (hg, j): half0 of qt=j then half1 of qt=15-j
// -> exactly 17 iters per block. Each half writes an l-normalized bf16 partial O +
// per-row (m,l); k_merge combines (all-masked halves: m=-1e30 -> weight 0).
#define ATTN_LDS 131072
__global__ __launch_bounds__(512, 1) void k_attn(const short* __restrict__ qb,
                                                 const short* __restrict__ kb,
                                                 const short* __restrict__ Vtg,
                                                 short* __restrict__ Po,
                                                 float* __restrict__ Pm,
                                                 float* __restrict__ Pl) {
  extern __shared__ char smem[];
  short* KbufS = (short*)smem;            // 2 bufs x [64 rows][32 chunks x 8]
  short* VbufS = (short*)(smem + 65536);  // 2 bufs x [256 rows][8 chunks x 8]

  const int raw = blockIdx.x;
  const int xcd = raw & 7, slot = raw >> 3;
  const int p = xcd >> 1, side = xcd & 1;
  const int id = side * 32 + slot;
  const int hgi = id & 3, j = id >> 2;
  const int b = p >> 1, kvh = p & 1, h = kvh * 4 + hgi;
  const int tid = threadIdx.x;
  const int w = tid >> 6, lane = tid & 63, lo = lane & 15, hi = lane >> 4;
  const int swz = lo & 7;

  const short* kbase = kb + ((size_t)(b * S_) * NKV_ + kvh) * HD_;
  const short* vbase = Vtg + (size_t)(b * 2 + kvh) * 256 * 2048;

  auto stage = [&](int kv0, int nb) {
#pragma unroll
    for (int rnd = 0; rnd < 4; ++rnd) {
      int i = rnd * 512 + tid;
      {
        int row = i >> 5, c = i & 31;
        const short* src = kbase + (size_t)(kv0 + row) * 512 + ((c ^ (row & 7)) * 8);
        gl16(src, smem + (size_t)nb * 32768 + (size_t)i * 16);
      }
      {
        int row = i >> 3, c = i & 7;
        const short* src = vbase + (size_t)row * 2048 + kv0 + ((c ^ (row & 7)) * 8);
        gl16(src, smem + 65536 + (size_t)nb * 32768 + (size_t)i * 16);
      }
    }
  };

#pragma unroll 1
  for (int part = 0; part < 2; ++part) {
    const int qt = part ? (15 - j) : j;
    const int q0 = qt * 128;
    const int t_begin = part ? (qt + 1) : 0;
    const int t_end = part ? (2 * qt + 2) : (qt + 1);

    s16x8 qf[8];
    {
      size_t base = ((size_t)((b * S_ + q0 + w * 16 + lo) * NH_) + h) * HD_;
#pragma unroll
      for (int t = 0; t < 8; ++t) qf[t] = *(const s16x8*)&qb[base + t * 32 + hi * 8];
    }
    f32x4 acc[16];
#pragma unroll
    for (int t = 0; t < 16; ++t) acc[t] = (f32x4){0.f, 0.f, 0.f, 0.f};
    float m_run = -1e30f, l_run = 0.f;
    const int qrow = q0 + w * 16 + lo;

    stage(t_begin * 64, 0);
    __syncthreads();

    int n = 0;
#pragma unroll 1
    for (int it = t_begin; it < t_end; ++it) {
      const int kv0 = it * 64;
      if (it + 1 < t_end) stage(kv0 + 64, n ^ 1);

      const short* Kb = KbufS + n * 16384;
      const short* Vb = VbufS + n * 16384;

      // S^T = K @ Q^T over HD=256 (swapped operands)
      f32x4 sacc[4] = {};
#pragma unroll
      for (int nt = 0; nt < 4; ++nt) {
        s16x8 kf[8];
#pragma unroll
        for (int t = 0; t < 8; ++t)
          kf[t] = *(const s16x8*)&Kb[(nt * 16 + lo) * 256 + (((t * 4 + hi) ^ swz) * 8)];
#pragma unroll
        for (int t = 0; t < 8; ++t)
          sacc[nt] = __builtin_amdgcn_mfma_f32_16x16x32_bf16(kf[t], qf[t], sacc[nt], 0, 0, 0);
      }

      // in-register softmax
      float pv[4][4];
      float mx = -1e30f;
#pragma unroll
      for (int nt = 0; nt < 4; ++nt)
#pragma unroll
        for (int r = 0; r < 4; ++r) {
          int kv = kv0 + nt * 16 + hi * 4 + r;
          float s = sacc[nt][r] * SCALE_;
          if (kv > qrow) s = -1e30f;
          pv[nt][r] = s;
          mx = fmaxf(mx, s);
        }
      mx = fmaxf(mx, __shfl_xor(mx, 16));
      mx = fmaxf(mx, __shfl_xor(mx, 32));
      if (!__all(mx <= m_run + 8.f)) {  // T13 defer-rescale
        float mnew = fmaxf(m_run, mx);
        float fs = __expf(m_run - mnew);
        m_run = mnew;
        l_run *= fs;
        float f0 = __shfl(fs, 4 * hi + 0);
        float f1 = __shfl(fs, 4 * hi + 1);
        float f2 = __shfl(fs, 4 * hi + 2);
        float f3 = __shfl(fs, 4 * hi + 3);
#pragma unroll
        for (int t = 0; t < 16; ++t) {
          acc[t][0] *= f0;
          acc[t][1] *= f1;
          acc[t][2] *= f2;
          acc[t][3] *= f3;
        }
      }
      float rs = 0.f;
#pragma unroll
      for (int nt = 0; nt < 4; ++nt)
#pragma unroll
        for (int r = 0; r < 4; ++r) {
          pv[nt][r] = __expf(pv[nt][r] - m_run);
          rs += pv[nt][r];
        }
      rs += __shfl_xor(rs, 16);
      rs += __shfl_xor(rs, 32);
      l_run += rs;

      // pack P to bf16 pairs
      int pk0[4], pk1[4];
#pragma unroll
      for (int nt = 0; nt < 4; ++nt) {
        asm("v_cvt_pk_bf16_f32 %0, %1, %2" : "=v"(pk0[nt]) : "v"(pv[nt][0]), "v"(pv[nt][1]));
        asm("v_cvt_pk_bf16_f32 %0, %1, %2" : "=v"(pk1[nt]) : "v"(pv[nt][2]), "v"(pv[nt][3]));
      }

      // PV: A-frag P[m=q=lo][k=kv] gathered via shfl from S^T owners
#pragma unroll
      for (int ks = 0; ks < 2; ++ks) {
        int pw[4];
#pragma unroll
        for (int dw = 0; dw < 4; ++dw) {
          int srcl = (2 * (hi & 1) + (dw >> 1)) * 16 + lo;
          int vA = __shfl((dw & 1) ? pk1[2 * ks] : pk0[2 * ks], srcl);
          int vB = __shfl((dw & 1) ? pk1[2 * ks + 1] : pk0[2 * ks + 1], srcl);
          pw[dw] = (hi & 2) ? vB : vA;
        }
        s16x8 pa;
        __builtin_memcpy(&pa, pw, 16);
#pragma unroll
        for (int g = 0; g < 2; ++g) {
          s16x8 vf[8];
#pragma unroll
          for (int u = 0; u < 8; ++u) {
            int t = g * 8 + u;
            vf[u] = *(const s16x8*)&Vb[(t * 16 + lo) * 64 + (((ks * 4 + hi) ^ swz) * 8)];
          }
#pragma unroll
          for (int u = 0; u < 8; ++u) {
            int t = g * 8 + u;
            acc[t] = __builtin_amdgcn_mfma_f32_16x16x32_bf16(pa, vf[u], acc[t], 0, 0, 0);
          }
        }
      }
      __syncthreads();
      n ^= 1;
    }

    // write l-normalized bf16 partial + (m,l) per row
    const int tile2 = ((b * 8 + h) * 16 + qt) * 2 + part;
    float linv[4];
#pragma unroll
    for (int r = 0; r < 4; ++r) {
      float lr = __shfl(l_run, 4 * hi + r);
      linv[r] = lr > 0.f ? 1.0f / lr : 0.f;
    }
#pragma unroll
    for (int t = 0; t < 16; ++t)
#pragma unroll
      for (int r = 0; r < 4; ++r)
        Po[(size_t)tile2 * 32768 + (w * 16 + hi * 4 + r) * 256 + t * 16 + lo] =
            f2bf(acc[t][r] * linv[r]);
    if (hi == 0) {
      Pm[tile2 * 128 + w * 16 + lo] = m_run;
      Pl[tile2 * 128 + w * 16 + lo] = l_run;
    }
  }
}

// ---------------- merge partials + sigmoid gate -> og ----------------
__global__ __launch_bounds__(256) void k_merge(const short* __restrict__ Po,
                                               const float* __restrict__ Pm,
                                               const float* __restrict__ Pl,
                                               const short* __restrict__ qg,
                                               short* __restrict__ og) {
  const int tile = blockIdx.x >> 4, rc = blockIdx.x & 15;
  const int b = tile >> 7, h = (tile >> 4) & 7, qt = tile & 15;
  const int t = threadIdx.x;
  const int r = t >> 5, rl = rc * 8 + r, c0 = (t & 31) * 8;
  const int row = qt * 128 + rl;
  const size_t base = (size_t)tile * 2 * 32768;
  s16x8 o0 = *(const s16x8*)&Po[base + rl * 256 + c0];
  s16x8 o1 = *(const s16x8*)&Po[base + 32768 + rl * 256 + c0];
  float m0 = Pm[tile * 256 + rl], m1 = Pm[tile * 256 + 128 + rl];
  float l0 = Pl[tile * 256 + rl], l1 = Pl[tile * 256 + 128 + rl];
  float mm = fmaxf(m0, m1);
  float w0 = l0 * __expf(m0 - mm), w1 = l1 * __expf(m1 - mm);
  float inv = 1.0f / (w0 + w1);
  s16x8 gv = *(const s16x8*)&qg[(size_t)(b * S_ + row) * 4096 + h * 512 + 256 + c0];
  s16x8 outv;
#pragma unroll
  for (int jj = 0; jj < 8; ++jj) {
    float o = (w0 * bf2f(o0[jj]) + w1 * bf2f(o1[jj])) * inv;
    float g = bf2f(gv[jj]);
    float sg = 1.0f / (1.0f + __expf(-g));
    outv[jj] = f2bf(o * sg);
  }
  *(s16x8*)&og[(size_t)(b * S_ + row) * 2048 + h * 256 + c0] = outv;
}

extern "C" void kernel_launch(void* const* d_in, const int* in_sizes, int n_in, void* d_out,
                              int out_size, void* d_ws, size_t ws_size, hipStream_t stream) {
  const float* hidden = (const float*)d_in[0];
  const float* cosb = (const float*)d_in[1];
  const float* sinb = (const float*)d_in[2];
  const float* Wq = (const float*)d_in[3];
  const float* Wk = (const float*)d_in[4];
  const float* Wv = (const float*)d_in[5];
  const float* Wo = (const float*)d_in[6];
  const float* qw = (const float*)d_in[7];
  const float* kw = (const float*)d_in[8];
  float* out = (float*)d_out;

  char* ws = (char*)d_ws;
  size_t off = 0;
  auto alloc = [&](size_t bytes) {
    void* p = ws + off;
    off += (bytes + 255) & ~(size_t)255;
    return p;
  };
  short* hb = (short*)alloc((size_t)TOK_ * HID_ * 2);
  short* WqT = (short*)alloc((size_t)4096 * 1024 * 2);
  short* kvT = (short*)alloc((size_t)1024 * 1024 * 2);
  short* WoT = (short*)alloc((size_t)1024 * 2048 * 2);
  short* qg = (short*)alloc((size_t)TOK_ * 4096 * 2);
  short* kvp = (short*)alloc((size_t)TOK_ * 1024 * 2);
  short* qb = (short*)alloc((size_t)TOK_ * 2048 * 2);
  short* kb = (short*)alloc((size_t)TOK_ * 512 * 2);
  short* og = (short*)alloc((size_t)TOK_ * 2048 * 2);
  short* Po = (short*)alloc((size_t)512 * 32768 * 2);
  float* Pm = (float*)alloc((size_t)512 * 128 * 4);
  float* Pl = (float*)alloc((size_t)512 * 128 * 4);
  short* Vtg = WqT;  // reuse: WqT dead after GEMM1
  (void)ws_size;
  (void)in_sizes;
  (void)n_in;
  (void)out_size;

  hipFuncSetAttribute((const void*)k_attn, hipFuncAttributeMaxDynamicSharedMemorySize,
                      ATTN_LDS);
  hipFuncSetAttribute((const void*)k_gemm256<1>, hipFuncAttributeMaxDynamicSharedMemorySize,
                      131072);
  hipFuncSetAttribute((const void*)k_gemm_bt<1>, hipFuncAttributeMaxDynamicSharedMemorySize,
                      65536);
  hipFuncSetAttribute((const void*)k_gemm_bt<0>, hipFuncAttributeMaxDynamicSharedMemorySize,
                      65536);

  k_cast<<<(TOK_ * HID_ + 255) / 256, 256, 0, stream>>>(hidden, hb, TOK_ * HID_);
  k_wtrans<<<dim3(4096 / 32, 1024 / 32), 256, 0, stream>>>(Wq, WqT, 1024, 4096);
  k_wtrans<<<dim3(512 / 32, 1024 / 32), 256, 0, stream>>>(Wk, kvT, 1024, 512);
  k_wtrans<<<dim3(512 / 32, 1024 / 32), 256, 0, stream>>>(Wv, kvT + 512 * 1024, 1024, 512);
  k_wtrans<<<dim3(1024 / 32, 2048 / 32), 256, 0, stream>>>(Wo, WoT, 2048, 1024);

  k_gemm256<1><<<dim3(16, 16), 512, 131072, stream>>>(hb, WqT, qg, 4096, 4096, 1024);
  k_gemm_bt<1><<<dim3(8, 32), 256, 65536, stream>>>(hb, kvT, kvp, 4096, 1024, 1024);

  k_norm_rope<NH_, 4096, 512><<<TOK_ * NH_, 256, 0, stream>>>(qg, qw, cosb, sinb, qb);
  k_norm_rope<NKV_, 1024, 256><<<TOK_ * NKV_, 256, 0, stream>>>(kvp, kw, cosb, sinb, kb);
  k_vtrans<<<dim3(64, 8, 4), 256, 0, stream>>>(kvp, Vtg);

  k_attn<<<256, 512, ATTN_LDS, stream>>>(qb, kb, Vtg, Po, Pm, Pl);
  k_merge<<<4096, 256, 0, stream>>>(Po, Pm, Pl, qg, og);

  k_gemm_bt<0><<<dim3(8, 32), 256, 65536, stream>>>(og, WoT, out, 4096, 1024, 2048);
}

// Round 19
// 206.870 us; speedup vs baseline: 1.1230x; 1.0045x over previous
//
#include <hip/hip_runtime.h>
#include <cstdint>
#include <cstddef>

#define B_ 2
#define S_ 2048
#define HID_ 1024
#define NH_ 8
#define NKV_ 2
#define HD_ 256
#define ROT_ 128
#define TOK_ (B_ * S_)
#define SCALE_ 0.0625f

typedef __attribute__((ext_vector_type(8))) short s16x8;
typedef __attribute__((ext_vector_type(4))) float f32x4;

__device__ __forceinline__ float bf2f(short u) {
  unsigned t = ((unsigned)(unsigned short)u) << 16;
  float f;
  __builtin_memcpy(&f, &t, 4);
  return f;
}
__device__ __forceinline__ short f2bf(float f) {
  unsigned u;
  __builtin_memcpy(&u, &f, 4);
  u += 0x7fffu + ((u >> 16) & 1);
  return (short)(u >> 16);
}

// async global->LDS 16B (gfx950). LDS dest is wave-uniform base + lane*16.
__device__ __forceinline__ void gl16(const void* g, void* l) {
  __builtin_amdgcn_global_load_lds((const __attribute__((address_space(1))) int*)g,
                                   (__attribute__((address_space(3))) int*)l, 16, 0, 0);
}

// ---------------- elementwise cast fp32 -> bf16 ----------------
__global__ __launch_bounds__(256) void k_cast(const float* __restrict__ in,
                                              short* __restrict__ out, int n) {
  int i = blockIdx.x * 256 + threadIdx.x;
  if (i < n) out[i] = f2bf(in[i]);
}

// ---------------- tiled transpose + cast: in[R][C] fp32 -> out[C][R] bf16 ----------------
__global__ __launch_bounds__(256) void k_wtrans(const float* __restrict__ in,
                                                short* __restrict__ out, int R, int C) {
  __shared__ short tile[32][33];
  int tx = threadIdx.x & 31, ty = threadIdx.x >> 5;
  int r0 = blockIdx.y * 32, c0 = blockIdx.x * 32;
#pragma unroll
  for (int p = 0; p < 4; ++p)
    tile[ty + p * 8][tx] = f2bf(in[(size_t)(r0 + ty + p * 8) * C + c0 + tx]);
  __syncthreads();
#pragma unroll
  for (int p = 0; p < 4; ++p)
    out[(size_t)(c0 + ty + p * 8) * R + r0 + tx] = tile[tx][ty + p * 8];
}

// ---------------- V transpose: kvp v-part -> Vtg[b*2+kvh][256][2048] bf16 ----------------
__global__ __launch_bounds__(256) void k_vtrans(const short* __restrict__ kvp,
                                                short* __restrict__ Vtg) {
  __shared__ short tile[32][33];
  int bh = blockIdx.z;
  int b = bh >> 1, kvh = bh & 1;
  int s0 = blockIdx.x * 32, d0 = blockIdx.y * 32;
  int tx = threadIdx.x & 31, ty = threadIdx.x >> 5;
#pragma unroll
  for (int p = 0; p < 4; ++p) {
    int sr = ty + p * 8;
    tile[sr][tx] = kvp[(size_t)(b * S_ + s0 + sr) * 1024 + 512 + kvh * 256 + d0 + tx];
  }
  __syncthreads();
#pragma unroll
  for (int p = 0; p < 4; ++p) {
    int dr = ty + p * 8;
    Vtg[((size_t)bh * 256 + d0 + dr) * 2048 + s0 + tx] = tile[tx][dr];
  }
}

// ---------------- GEMM 128x128, BK=64, 2-phase dbuf, 8 waves (2 waves/SIMD) ---------
// Same tile/staging/swizzle as before but 512 threads: wave (w>>2, w&3) owns a 64x32
// sub-tile (4x2 frags, 16 MFMA/K-tile). At 256-block grids this kernel previously ran
// 4 waves = 1 wave/SIMD (zero TLP); 8 waves = 2/SIMD hides the per-K-tile vmcnt drain.
template <int OUT_BF16>
__global__ __launch_bounds__(512, 1) void k_gemm_bt(const short* __restrict__ A,
                                                    const short* __restrict__ Bt,
                                                    void* __restrict__ Cv, int M, int N,
                                                    int K) {
  extern __shared__ char smem[];
  const int tid = threadIdx.x;
  const int bm = blockIdx.y * 128, bn = blockIdx.x * 128;
  const int w = tid >> 6, lane = tid & 63, lo = lane & 15, hi = lane >> 4;
  const int wr = (w >> 2) * 64, wc = (w & 3) * 32;
  f32x4 acc[4][2] = {};

  auto stage = [&](int k0, int nb) {
#pragma unroll
    for (int rnd = 0; rnd < 2; ++rnd) {
      int i = rnd * 512 + tid;  // slot 0..1023
      int row = i >> 3, c = i & 7;
      int src_col = (c ^ (row & 7)) * 8;
      gl16(&A[(size_t)(bm + row) * K + k0 + src_col], smem + (size_t)nb * 16384 + (size_t)i * 16);
      gl16(&Bt[(size_t)(bn + row) * K + k0 + src_col],
           smem + 32768 + (size_t)nb * 16384 + (size_t)i * 16);
    }
  };

  stage(0, 0);
  __syncthreads();
  int nb = 0;
  for (int k0 = 0; k0 < K; k0 += 64) {
    if (k0 + 64 < K) stage(k0 + 64, nb ^ 1);
    const short* As = (const short*)(smem + (size_t)nb * 16384);
    const short* Bs = (const short*)(smem + 32768 + (size_t)nb * 16384);
    s16x8 af[2][4], bfr[2][2];
#pragma unroll
    for (int kk = 0; kk < 2; ++kk) {
#pragma unroll
      for (int m = 0; m < 4; ++m) {
        int row = wr + m * 16 + lo;
        af[kk][m] = *(const s16x8*)&As[row * 64 + (((kk * 4 + hi) ^ (row & 7)) * 8)];
      }
#pragma unroll
      for (int n = 0; n < 2; ++n) {
        int row = wc + n * 16 + lo;
        bfr[kk][n] = *(const s16x8*)&Bs[row * 64 + (((kk * 4 + hi) ^ (row & 7)) * 8)];
      }
    }
#pragma unroll
    for (int kk = 0; kk < 2; ++kk)
#pragma unroll
      for (int m = 0; m < 4; ++m)
#pragma unroll
        for (int n = 0; n < 2; ++n)
          acc[m][n] =
              __builtin_amdgcn_mfma_f32_16x16x32_bf16(af[kk][m], bfr[kk][n], acc[m][n], 0, 0, 0);
    __syncthreads();
    nb ^= 1;
  }
#pragma unroll
  for (int m = 0; m < 4; ++m)
#pragma unroll
    for (int n = 0; n < 2; ++n)
#pragma unroll
      for (int r = 0; r < 4; ++r) {
        int row = bm + wr + m * 16 + hi * 4 + r;
        int col = bn + wc + n * 16 + lo;
        if (OUT_BF16)
          ((short*)Cv)[(size_t)row * N + col] = f2bf(acc[m][n][r]);
        else
          ((float*)Cv)[(size_t)row * N + col] = acc[m][n][r];
      }
}

// ---------------- GEMM 256x256, 8 waves, BK=64, 2-phase double-buffered (best) ------
template <int OUT_BF16>
__global__ __launch_bounds__(512, 1) void k_gemm256(const short* __restrict__ A,
                                                    const short* __restrict__ Bt,
                                                    void* __restrict__ Cv, int M, int N,
                                                    int K) {
  extern __shared__ char smem[];
  const int tid = threadIdx.x;
  const int bm = blockIdx.y * 256, bn = blockIdx.x * 256;
  const int w = tid >> 6, lane = tid & 63, lo = lane & 15, hi = lane >> 4;
  const int wr = (w >> 2) * 128, wc = (w & 3) * 64;
  f32x4 acc[8][4] = {};

  auto stage = [&](int k0, int nb) {
#pragma unroll
    for (int rnd = 0; rnd < 4; ++rnd) {
      int i = rnd * 512 + tid;
      int row = i >> 3, c = i & 7;
      int src_col = (c ^ (row & 7)) * 8;
      gl16(&A[(size_t)(bm + row) * K + k0 + src_col], smem + (size_t)nb * 32768 + (size_t)i * 16);
      gl16(&Bt[(size_t)(bn + row) * K + k0 + src_col],
           smem + 65536 + (size_t)nb * 32768 + (size_t)i * 16);
    }
  };

  stage(0, 0);
  __syncthreads();
  int nb = 0;
  for (int k0 = 0; k0 < K; k0 += 64) {
    if (k0 + 64 < K) stage(k0 + 64, nb ^ 1);
    const short* As = (const short*)(smem + (size_t)nb * 32768);
    const short* Bs = (const short*)(smem + 65536 + (size_t)nb * 32768);
#pragma unroll
    for (int kk = 0; kk < 2; ++kk) {
      s16x8 bfr[4];
#pragma unroll
      for (int n = 0; n < 4; ++n) {
        int row = wc + n * 16 + lo;
        bfr[n] = *(const s16x8*)&Bs[row * 64 + (((kk * 4 + hi) ^ (row & 7)) * 8)];
      }
#pragma unroll
      for (int g = 0; g < 2; ++g) {
        s16x8 af[4];
#pragma unroll
        for (int u = 0; u < 4; ++u) {
          int row = wr + (g * 4 + u) * 16 + lo;
          af[u] = *(const s16x8*)&As[row * 64 + (((kk * 4 + hi) ^ (row & 7)) * 8)];
        }
#pragma unroll
        for (int u = 0; u < 4; ++u)
#pragma unroll
          for (int n = 0; n < 4; ++n)
            acc[g * 4 + u][n] =
                __builtin_amdgcn_mfma_f32_16x16x32_bf16(af[u], bfr[n], acc[g * 4 + u][n], 0, 0, 0);
      }
    }
    __syncthreads();
    nb ^= 1;
  }
#pragma unroll
  for (int m = 0; m < 8; ++m)
#pragma unroll
    for (int n = 0; n < 4; ++n)
#pragma unroll
      for (int r = 0; r < 4; ++r) {
        int row = bm + wr + m * 16 + hi * 4 + r;
        int col = bn + wc + n * 16 + lo;
        if (OUT_BF16)
          ((short*)Cv)[(size_t)row * N + col] = f2bf(acc[m][n][r]);
        else
          ((float*)Cv)[(size_t)row * N + col] = acc[m][n][r];
      }
}

// ---------------- per-(token,head) RMSNorm + RoPE, bf16 in/out ----------------
template <int NHEAD, int IN_ROW, int IN_HS>
__global__ __launch_bounds__(256) void k_norm_rope(const short* __restrict__ xin,
                                                   const float* __restrict__ wn,
                                                   const float* __restrict__ cosb,
                                                   const float* __restrict__ sinb,
                                                   short* __restrict__ xout) {
  int blk = blockIdx.x;
  int h = blk % NHEAD;
  int ts = blk / NHEAD;
  int d = threadIdx.x;
  float x = bf2f(xin[(size_t)ts * IN_ROW + h * IN_HS + d]);
  float ss = x * x;
#pragma unroll
  for (int m = 32; m >= 1; m >>= 1) ss += __shfl_xor(ss, m);
  __shared__ float sred[4];
  __shared__ float sn[256];
  int wid = d >> 6;
  if ((d & 63) == 0) sred[wid] = ss;
  __syncthreads();
  float tot = sred[0] + sred[1] + sred[2] + sred[3];
  float nv = x * rsqrtf(tot * (1.0f / 256.0f) + 1e-6f) * (1.0f + wn[d]);
  sn[d] = nv;
  __syncthreads();
  float o;
  if (d < 128) {
    float c = cosb[(size_t)ts * 128 + d];
    float s = sinb[(size_t)ts * 128 + d];
    o = (d < 64) ? (nv * c - sn[d + 64] * s) : (nv * c + sn[d - 64] * s);
  } else {
    o = nv;
  }
  xout[(size_t)blk * 256 + d] = f2bf(o);
}

// ---------------- GQA causal flash attention, balanced KV-split (R15, best) ---------
// 256 blocks, 8 waves, QBLK=128. Block (hg, j): half0 of qt=j then half1 of qt=15-j
// -> exactly 17 iters per block. Each half writes an l-normalized bf16 partial O +
// per-row (m,l); k_merge combines (all-masked halves: m=-1e30 -> weight 0).
#define ATTN_LDS 131072
__global__ __launch_bounds__(512, 1) void k_attn(const short* __restrict__ qb,
                                                 const short* __restrict__ kb,
                                                 const short* __restrict__ Vtg,
                                                 short* __restrict__ Po,
                                                 float* __restrict__ Pm,
                                                 float* __restrict__ Pl) {
  extern __shared__ char smem[];
  short* KbufS = (short*)smem;            // 2 bufs x [64 rows][32 chunks x 8]
  short* VbufS = (short*)(smem + 65536);  // 2 bufs x [256 rows][8 chunks x 8]

  const int raw = blockIdx.x;
  const int xcd = raw & 7, slot = raw >> 3;
  const int p = xcd >> 1, side = xcd & 1;
  const int id = side * 32 + slot;
  const int hgi = id & 3, j = id >> 2;
  const int b = p >> 1, kvh = p & 1, h = kvh * 4 + hgi;
  const int tid = threadIdx.x;
  const int w = tid >> 6, lane = tid & 63, lo = lane & 15, hi = lane >> 4;
  const int swz = lo & 7;

  const short* kbase = kb + ((size_t)(b * S_) * NKV_ + kvh) * HD_;
  const short* vbase = Vtg + (size_t)(b * 2 + kvh) * 256 * 2048;

  auto stage = [&](int kv0, int nb) {
#pragma unroll
    for (int rnd = 0; rnd < 4; ++rnd) {
      int i = rnd * 512 + tid;
      {
        int row = i >> 5, c = i & 31;
        const short* src = kbase + (size_t)(kv0 + row) * 512 + ((c ^ (row & 7)) * 8);
        gl16(src, smem + (size_t)nb * 32768 + (size_t)i * 16);
      }
      {
        int row = i >> 3, c = i & 7;
        const short* src = vbase + (size_t)row * 2048 + kv0 + ((c ^ (row & 7)) * 8);
        gl16(src, smem + 65536 + (size_t)nb * 32768 + (size_t)i * 16);
      }
    }
  };

#pragma unroll 1
  for (int part = 0; part < 2; ++part) {
    const int qt = part ? (15 - j) : j;
    const int q0 = qt * 128;
    const int t_begin = part ? (qt + 1) : 0;
    const int t_end = part ? (2 * qt + 2) : (qt + 1);

    s16x8 qf[8];
    {
      size_t base = ((size_t)((b * S_ + q0 + w * 16 + lo) * NH_) + h) * HD_;
#pragma unroll
      for (int t = 0; t < 8; ++t) qf[t] = *(const s16x8*)&qb[base + t * 32 + hi * 8];
    }
    f32x4 acc[16];
#pragma unroll
    for (int t = 0; t < 16; ++t) acc[t] = (f32x4){0.f, 0.f, 0.f, 0.f};
    float m_run = -1e30f, l_run = 0.f;
    const int qrow = q0 + w * 16 + lo;

    stage(t_begin * 64, 0);
    __syncthreads();

    int n = 0;
#pragma unroll 1
    for (int it = t_begin; it < t_end; ++it) {
      const int kv0 = it * 64;
      if (it + 1 < t_end) stage(kv0 + 64, n ^ 1);

      const short* Kb = KbufS + n * 16384;
      const short* Vb = VbufS + n * 16384;

      // S^T = K @ Q^T over HD=256 (swapped operands)
      f32x4 sacc[4] = {};
#pragma unroll
      for (int nt = 0; nt < 4; ++nt) {
        s16x8 kf[8];
#pragma unroll
        for (int t = 0; t < 8; ++t)
          kf[t] = *(const s16x8*)&Kb[(nt * 16 + lo) * 256 + (((t * 4 + hi) ^ swz) * 8)];
#pragma unroll
        for (int t = 0; t < 8; ++t)
          sacc[nt] = __builtin_amdgcn_mfma_f32_16x16x32_bf16(kf[t], qf[t], sacc[nt], 0, 0, 0);
      }

      // in-register softmax
      float pv[4][4];
      float mx = -1e30f;
#pragma unroll
      for (int nt = 0; nt < 4; ++nt)
#pragma unroll
        for (int r = 0; r < 4; ++r) {
          int kv = kv0 + nt * 16 + hi * 4 + r;
          float s = sacc[nt][r] * SCALE_;
          if (kv > qrow) s = -1e30f;
          pv[nt][r] = s;
          mx = fmaxf(mx, s);
        }
      mx = fmaxf(mx, __shfl_xor(mx, 16));
      mx = fmaxf(mx, __shfl_xor(mx, 32));
      if (!__all(mx <= m_run + 8.f)) {  // T13 defer-rescale
        float mnew = fmaxf(m_run, mx);
        float fs = __expf(m_run - mnew);
        m_run = mnew;
        l_run *= fs;
        float f0 = __shfl(fs, 4 * hi + 0);
        float f1 = __shfl(fs, 4 * hi + 1);
        float f2 = __shfl(fs, 4 * hi + 2);
        float f3 = __shfl(fs, 4 * hi + 3);
#pragma unroll
        for (int t = 0; t < 16; ++t) {
          acc[t][0] *= f0;
          acc[t][1] *= f1;
          acc[t][2] *= f2;
          acc[t][3] *= f3;
        }
      }
      float rs = 0.f;
#pragma unroll
      for (int nt = 0; nt < 4; ++nt)
#pragma unroll
        for (int r = 0; r < 4; ++r) {
          pv[nt][r] = __expf(pv[nt][r] - m_run);
          rs += pv[nt][r];
        }
      rs += __shfl_xor(rs, 16);
      rs += __shfl_xor(rs, 32);
      l_run += rs;

      // pack P to bf16 pairs
      int pk0[4], pk1[4];
#pragma unroll
      for (int nt = 0; nt < 4; ++nt) {
        asm("v_cvt_pk_bf16_f32 %0, %1, %2" : "=v"(pk0[nt]) : "v"(pv[nt][0]), "v"(pv[nt][1]));
        asm("v_cvt_pk_bf16_f32 %0, %1, %2" : "=v"(pk1[nt]) : "v"(pv[nt][2]), "v"(pv[nt][3]));
      }

      // PV: A-frag P[m=q=lo][k=kv] gathered via shfl from S^T owners
#pragma unroll
      for (int ks = 0; ks < 2; ++ks) {
        int pw[4];
#pragma unroll
        for (int dw = 0; dw < 4; ++dw) {
          int srcl = (2 * (hi & 1) + (dw >> 1)) * 16 + lo;
          int vA = __shfl((dw & 1) ? pk1[2 * ks] : pk0[2 * ks], srcl);
          int vB = __shfl((dw & 1) ? pk1[2 * ks + 1] : pk0[2 * ks + 1], srcl);
          pw[dw] = (hi & 2) ? vB : vA;
        }
        s16x8 pa;
        __builtin_memcpy(&pa, pw, 16);
#pragma unroll
        for (int g = 0; g < 2; ++g) {
          s16x8 vf[8];
#pragma unroll
          for (int u = 0; u < 8; ++u) {
            int t = g * 8 + u;
            vf[u] = *(const s16x8*)&Vb[(t * 16 + lo) * 64 + (((ks * 4 + hi) ^ swz) * 8)];
          }
#pragma unroll
          for (int u = 0; u < 8; ++u) {
            int t = g * 8 + u;
            acc[t] = __builtin_amdgcn_mfma_f32_16x16x32_bf16(pa, vf[u], acc[t], 0, 0, 0);
          }
        }
      }
      __syncthreads();
      n ^= 1;
    }

    // write l-normalized bf16 partial + (m,l) per row
    const int tile2 = ((b * 8 + h) * 16 + qt) * 2 + part;
    float linv[4];
#pragma unroll
    for (int r = 0; r < 4; ++r) {
      float lr = __shfl(l_run, 4 * hi + r);
      linv[r] = lr > 0.f ? 1.0f / lr : 0.f;
    }
#pragma unroll
    for (int t = 0; t < 16; ++t)
#pragma unroll
      for (int r = 0; r < 4; ++r)
        Po[(size_t)tile2 * 32768 + (w * 16 + hi * 4 + r) * 256 + t * 16 + lo] =
            f2bf(acc[t][r] * linv[r]);
    if (hi == 0) {
      Pm[tile2 * 128 + w * 16 + lo] = m_run;
      Pl[tile2 * 128 + w * 16 + lo] = l_run;
    }
  }
}

// ---------------- merge partials + sigmoid gate -> og ----------------
__global__ __launch_bounds__(256) void k_merge(const short* __restrict__ Po,
                                               const float* __restrict__ Pm,
                                               const float* __restrict__ Pl,
                                               const short* __restrict__ qg,
                                               short* __restrict__ og) {
  const int tile = blockIdx.x >> 4, rc = blockIdx.x & 15;
  const int b = tile >> 7, h = (tile >> 4) & 7, qt = tile & 15;
  const int t = threadIdx.x;
  const int r = t >> 5, rl = rc * 8 + r, c0 = (t & 31) * 8;
  const int row = qt * 128 + rl;
  const size_t base = (size_t)tile * 2 * 32768;
  s16x8 o0 = *(const s16x8*)&Po[base + rl * 256 + c0];
  s16x8 o1 = *(const s16x8*)&Po[base + 32768 + rl * 256 + c0];
  float m0 = Pm[tile * 256 + rl], m1 = Pm[tile * 256 + 128 + rl];
  float l0 = Pl[tile * 256 + rl], l1 = Pl[tile * 256 + 128 + rl];
  float mm = fmaxf(m0, m1);
  float w0 = l0 * __expf(m0 - mm), w1 = l1 * __expf(m1 - mm);
  float inv = 1.0f / (w0 + w1);
  s16x8 gv = *(const s16x8*)&qg[(size_t)(b * S_ + row) * 4096 + h * 512 + 256 + c0];
  s16x8 outv;
#pragma unroll
  for (int jj = 0; jj < 8; ++jj) {
    float o = (w0 * bf2f(o0[jj]) + w1 * bf2f(o1[jj])) * inv;
    float g = bf2f(gv[jj]);
    float sg = 1.0f / (1.0f + __expf(-g));
    outv[jj] = f2bf(o * sg);
  }
  *(s16x8*)&og[(size_t)(b * S_ + row) * 2048 + h * 256 + c0] = outv;
}

extern "C" void kernel_launch(void* const* d_in, const int* in_sizes, int n_in, void* d_out,
                              int out_size, void* d_ws, size_t ws_size, hipStream_t stream) {
  const float* hidden = (const float*)d_in[0];
  const float* cosb = (const float*)d_in[1];
  const float* sinb = (const float*)d_in[2];
  const float* Wq = (const float*)d_in[3];
  const float* Wk = (const float*)d_in[4];
  const float* Wv = (const float*)d_in[5];
  const float* Wo = (const float*)d_in[6];
  const float* qw = (const float*)d_in[7];
  const float* kw = (const float*)d_in[8];
  float* out = (float*)d_out;

  char* ws = (char*)d_ws;
  size_t off = 0;
  auto alloc = [&](size_t bytes) {
    void* p = ws + off;
    off += (bytes + 255) & ~(size_t)255;
    return p;
  };
  short* hb = (short*)alloc((size_t)TOK_ * HID_ * 2);
  short* WqT = (short*)alloc((size_t)4096 * 1024 * 2);
  short* kvT = (short*)alloc((size_t)1024 * 1024 * 2);
  short* WoT = (short*)alloc((size_t)1024 * 2048 * 2);
  short* qg = (short*)alloc((size_t)TOK_ * 4096 * 2);
  short* kvp = (short*)alloc((size_t)TOK_ * 1024 * 2);
  short* qb = (short*)alloc((size_t)TOK_ * 2048 * 2);
  short* kb = (short*)alloc((size_t)TOK_ * 512 * 2);
  short* og = (short*)alloc((size_t)TOK_ * 2048 * 2);
  short* Po = (short*)alloc((size_t)512 * 32768 * 2);
  float* Pm = (float*)alloc((size_t)512 * 128 * 4);
  float* Pl = (float*)alloc((size_t)512 * 128 * 4);
  short* Vtg = WqT;  // reuse: WqT dead after GEMM1
  (void)ws_size;
  (void)in_sizes;
  (void)n_in;
  (void)out_size;

  hipFuncSetAttribute((const void*)k_attn, hipFuncAttributeMaxDynamicSharedMemorySize,
                      ATTN_LDS);
  hipFuncSetAttribute((const void*)k_gemm256<1>, hipFuncAttributeMaxDynamicSharedMemorySize,
                      131072);
  hipFuncSetAttribute((const void*)k_gemm_bt<1>, hipFuncAttributeMaxDynamicSharedMemorySize,
                      65536);
  hipFuncSetAttribute((const void*)k_gemm_bt<0>, hipFuncAttributeMaxDynamicSharedMemorySize,
                      65536);

  k_cast<<<(TOK_ * HID_ + 255) / 256, 256, 0, stream>>>(hidden, hb, TOK_ * HID_);
  k_wtrans<<<dim3(4096 / 32, 1024 / 32), 256, 0, stream>>>(Wq, WqT, 1024, 4096);
  k_wtrans<<<dim3(512 / 32, 1024 / 32), 256, 0, stream>>>(Wk, kvT, 1024, 512);
  k_wtrans<<<dim3(512 / 32, 1024 / 32), 256, 0, stream>>>(Wv, kvT + 512 * 1024, 1024, 512);
  k_wtrans<<<dim3(1024 / 32, 2048 / 32), 256, 0, stream>>>(Wo, WoT, 2048, 1024);

  k_gemm256<1><<<dim3(16, 16), 512, 131072, stream>>>(hb, WqT, qg, 4096, 4096, 1024);
  k_gemm_bt<1><<<dim3(8, 32), 512, 65536, stream>>>(hb, kvT, kvp, 4096, 1024, 1024);

  k_norm_rope<NH_, 4096, 512><<<TOK_ * NH_, 256, 0, stream>>>(qg, qw, cosb, sinb, qb);
  k_norm_rope<NKV_, 1024, 256><<<TOK_ * NKV_, 256, 0, stream>>>(kvp, kw, cosb, sinb, kb);
  k_vtrans<<<dim3(64, 8, 4), 256, 0, stream>>>(kvp, Vtg);

  k_attn<<<256, 512, ATTN_LDS, stream>>>(qb, kb, Vtg, Po, Pm, Pl);
  k_merge<<<4096, 256, 0, stream>>>(Po, Pm, Pl, qg, og);

  k_gemm_bt<0><<<dim3(8, 32), 512, 65536, stream>>>(og, WoT, out, 4096, 1024, 2048);
}